// Round 1
// baseline (1566.156 us; speedup 1.0000x reference)
//
#include <hip/hip_runtime.h>

#define N_TOK 16384
#define DMODEL 1024
#define NEXP 8
#define CAP 4096
#define HDIM 4096

typedef unsigned short ushort_t;
typedef unsigned int u32;
typedef __attribute__((ext_vector_type(8))) _Float16 half8;
typedef __attribute__((ext_vector_type(8))) ushort_t ushort8;
typedef __attribute__((ext_vector_type(4))) float f32x4;

__device__ inline ushort_t f2h_bits(float f) {
  _Float16 h = (_Float16)f;
  union { _Float16 h; ushort_t u; } cv;
  cv.h = h;
  return cv.u;
}

// async global->LDS, 16B per lane; lds dest is wave-uniform base + lane*16
__device__ inline void gll16(void* lds, const void* g) {
  __builtin_amdgcn_global_load_lds((const __attribute__((address_space(1))) u32*)g,
                                   (__attribute__((address_space(3))) u32*)lds,
                                   16, 0, 0);
}

// ---------------- router: logits, noisy top-2, gates ----------------
__global__ __launch_bounds__(256) void router_kernel(
    const float* __restrict__ x, const float* __restrict__ noise,
    const float* __restrict__ Wr, const float* __restrict__ br,
    const float* __restrict__ Wn, const float* __restrict__ bn,
    int* __restrict__ topi, float* __restrict__ tgate) {
  __shared__ float wrT[NEXP * DMODEL];   // transposed: [e][d] -> conflict-free reads
  __shared__ float wnT[NEXP * DMODEL];
  int tid = threadIdx.x;
  for (int i = tid; i < NEXP * DMODEL; i += 256) {
    int d = i >> 3, e = i & 7;
    wrT[e * DMODEL + d] = Wr[i];
    wnT[e * DMODEL + d] = Wn[i];
  }
  __syncthreads();
  int wave = tid >> 6, lane = tid & 63;
  for (int t = blockIdx.x * 4 + wave; t < N_TOK; t += gridDim.x * 4) {
    float aR[NEXP], aN[NEXP];
#pragma unroll
    for (int e = 0; e < NEXP; ++e) { aR[e] = 0.f; aN[e] = 0.f; }
#pragma unroll 4
    for (int it = 0; it < 16; ++it) {
      int d = lane + it * 64;
      float xv = x[(size_t)t * DMODEL + d];
#pragma unroll
      for (int e = 0; e < NEXP; ++e) {
        aR[e] = fmaf(xv, wrT[e * DMODEL + d], aR[e]);
        aN[e] = fmaf(xv, wnT[e * DMODEL + d], aN[e]);
      }
    }
#pragma unroll
    for (int e = 0; e < NEXP; ++e) {
#pragma unroll
      for (int off = 32; off > 0; off >>= 1) {
        aR[e] += __shfl_xor(aR[e], off);
        aN[e] += __shfl_xor(aN[e], off);
      }
    }
    if (lane == 0) {
      float v0 = -1e30f, v1 = -1e30f;
      int i0 = 0, i1 = 0;
#pragma unroll
      for (int e = 0; e < NEXP; ++e) {
        float lg = aR[e] + br[e];
        float nl = aN[e] + bn[e];
        float sp = fmaxf(nl, 0.f) + log1pf(expf(-fabsf(nl)));   // stable softplus
        float nz = fmaf(noise[(size_t)t * NEXP + e], sp, lg);
        if (nz > v0) { v1 = v0; i1 = i0; v0 = nz; i0 = e; }      // strict > : earliest idx wins ties (lax.top_k)
        else if (nz > v1) { v1 = nz; i1 = e; }
      }
      float e1 = expf(v1 - v0);   // <= 1
      float s = 1.f + e1;
      topi[t * 2] = i0;
      topi[t * 2 + 1] = i1;
      tgate[t * 2] = 1.f / s;
      tgate[t * 2 + 1] = e1 / s;
    }
  }
}

// ------------- scan: arrival-order slots per expert, capacity clamp -------------
__global__ __launch_bounds__(1024) void scan_kernel(
    const int* __restrict__ topi, const float* __restrict__ tgate,
    int* __restrict__ tokL, float* __restrict__ gateL, int* __restrict__ counts) {
  __shared__ int s[NEXP][1024];
  __shared__ int run[NEXP][1024];
  int t = threadIdx.x;
#pragma unroll
  for (int e = 0; e < NEXP; ++e) s[e][t] = 0;
  // count my 16 tokens (own column only -> no races)
#pragma unroll
  for (int i = 0; i < 16; ++i) {
    int n = t * 16 + i;
    s[topi[n * 2]][t]++;
    s[topi[n * 2 + 1]][t]++;
  }
  int myc[NEXP];
#pragma unroll
  for (int e = 0; e < NEXP; ++e) myc[e] = s[e][t];
  __syncthreads();
  // inclusive Hillis-Steele over 1024 threads, 8 experts at once
  for (int off = 1; off < 1024; off <<= 1) {
    int v[NEXP];
#pragma unroll
    for (int e = 0; e < NEXP; ++e) v[e] = (t >= off) ? s[e][t - off] : 0;
    __syncthreads();
#pragma unroll
    for (int e = 0; e < NEXP; ++e) s[e][t] += v[e];
    __syncthreads();
  }
#pragma unroll
  for (int e = 0; e < NEXP; ++e) run[e][t] = s[e][t] - myc[e];  // exclusive base
  if (t == 1023) {
#pragma unroll
    for (int e = 0; e < NEXP; ++e) counts[e] = (s[e][1023] < CAP) ? s[e][1023] : CAP;
  }
  // replay in order, assign slots
#pragma unroll
  for (int i = 0; i < 16; ++i) {
    int n = t * 16 + i;
#pragma unroll
    for (int k = 0; k < 2; ++k) {
      int e = topi[n * 2 + k];
      int slot = run[e][t]++;
      if (slot < CAP) {
        tokL[e * CAP + slot] = n;
        gateL[e * CAP + slot] = tgate[n * 2 + k];
      }
    }
  }
}

// ------------- gather expert's tokens into compact f16 matrix -------------
__global__ __launch_bounds__(256) void gather_kernel(
    const float* __restrict__ x, const int* __restrict__ etok,
    const int* __restrict__ counts, int e, ushort_t* __restrict__ Xg) {
  int ne = counts[e];
  int slot = blockIdx.x * 2 + (threadIdx.x >> 7);
  if (slot >= ne) return;
  int tok = etok[slot];
  int c = (threadIdx.x & 127) * 8;
  const float4* src = (const float4*)(x + (size_t)tok * DMODEL + c);
  float4 v0 = src[0], v1 = src[1];
  ushort8 o;
  o[0] = f2h_bits(v0.x); o[1] = f2h_bits(v0.y); o[2] = f2h_bits(v0.z); o[3] = f2h_bits(v0.w);
  o[4] = f2h_bits(v1.x); o[5] = f2h_bits(v1.y); o[6] = f2h_bits(v1.z); o[7] = f2h_bits(v1.w);
  *(ushort8*)(Xg + (size_t)slot * DMODEL + c) = o;
}

// ------------- transpose fp32 [R][C] -> f16 [C][R] -------------
__global__ __launch_bounds__(256) void transpose_cvt_kernel(
    const float* __restrict__ in, ushort_t* __restrict__ out, int R, int C) {
  __shared__ float tile[32][33];
  int c0 = blockIdx.x * 32, r0 = blockIdx.y * 32;
  int xx = threadIdx.x, yy = threadIdx.y;   // block (32,8)
#pragma unroll
  for (int i = 0; i < 4; ++i) {
    int r = yy + i * 8;
    tile[r][xx] = in[(size_t)(r0 + r) * C + c0 + xx];
  }
  __syncthreads();
#pragma unroll
  for (int i = 0; i < 4; ++i) {
    int r = yy + i * 8;
    out[(size_t)(c0 + r) * R + r0 + xx] = f2h_bits(tile[xx][r]);
  }
}

// ------------- 128x128 f16 MFMA GEMM, m97 structure -------------
// A: [>=M][Kdim] f16 row-major ; Bt: [N][Kdim] f16 (i.e. B transposed)
// EPI 0: H[row][col] = f16(relu(acc + bias[col]))
// EPI 1: atomicAdd(out[etok[row]*DMODEL + col], (acc + bias[col]) * egate[row])
template <int EPI>
__global__ __launch_bounds__(256) void moe_gemm(
    const ushort_t* __restrict__ A, const ushort_t* __restrict__ Bt, int Kdim,
    const int* __restrict__ counts, int e, const float* __restrict__ bias,
    ushort_t* __restrict__ H,
    const int* __restrict__ etok, const float* __restrict__ egate,
    float* __restrict__ out) {
  int ne = counts[e];
  int row0 = blockIdx.y * 128;
  if (row0 >= ne) return;
  int col0 = blockIdx.x * 128;
  __shared__ __align__(16) ushort_t lds_a[128 * 32];
  __shared__ __align__(16) ushort_t lds_b[128 * 32];
  int tid = threadIdx.x, wave = tid >> 6, lane = tid & 63;
  int wr = wave >> 1, wc = wave & 1;
  f32x4 acc[4][4];
#pragma unroll
  for (int m = 0; m < 4; ++m)
#pragma unroll
    for (int n = 0; n < 4; ++n) acc[m][n] = f32x4{0.f, 0.f, 0.f, 0.f};
  int srow = lane >> 2;            // row within 16-row staging chunk
  int soff = (lane & 3) * 16;      // byte offset within 64B row
  const char* Ab = (const char*)A;
  const char* Bb = (const char*)Bt;
  size_t stride = (size_t)Kdim * 2;
  int lr = lane & 15, lk = (lane >> 4) * 8;
  for (int kt = 0; kt < Kdim; kt += 32) {
#pragma unroll
    for (int i = 0; i < 2; ++i) {
      int c = wave + i * 4;        // 8 chunks of 16 rows x 64B
      gll16((char*)lds_a + c * 1024,
            Ab + (size_t)(row0 + c * 16 + srow) * stride + (size_t)kt * 2 + soff);
      gll16((char*)lds_b + c * 1024,
            Bb + (size_t)(col0 + c * 16 + srow) * stride + (size_t)kt * 2 + soff);
    }
    __syncthreads();               // compiler emits vmcnt(0) drain before barrier
    half8 af[4], bfr[4];
#pragma unroll
    for (int m = 0; m < 4; ++m)
      af[m] = *(const half8*)&lds_a[(wr * 64 + m * 16 + lr) * 32 + lk];
#pragma unroll
    for (int n = 0; n < 4; ++n)
      bfr[n] = *(const half8*)&lds_b[(wc * 64 + n * 16 + lr) * 32 + lk];
#pragma unroll
    for (int m = 0; m < 4; ++m)
#pragma unroll
      for (int n = 0; n < 4; ++n)
        acc[m][n] = __builtin_amdgcn_mfma_f32_16x16x32_f16(af[m], bfr[n], acc[m][n], 0, 0, 0);
    __syncthreads();
  }
  int lq = (lane >> 4) * 4;
  if (EPI == 0) {
#pragma unroll
    for (int n = 0; n < 4; ++n) {
      int col = col0 + wc * 64 + n * 16 + lr;
      float bv = bias[col];
#pragma unroll
      for (int m = 0; m < 4; ++m) {
#pragma unroll
        for (int j = 0; j < 4; ++j) {
          int row = row0 + wr * 64 + m * 16 + lq + j;
          float v = acc[m][n][j] + bv;
          H[(size_t)row * HDIM + col] = f2h_bits(fmaxf(v, 0.f));
        }
      }
    }
  } else {
    float bv[4];
#pragma unroll
    for (int n = 0; n < 4; ++n) bv[n] = bias[col0 + wc * 64 + n * 16 + lr];
#pragma unroll
    for (int m = 0; m < 4; ++m) {
#pragma unroll
      for (int j = 0; j < 4; ++j) {
        int row = row0 + wr * 64 + m * 16 + lq + j;
        if (row < ne) {
          int tok = etok[row];
          float g = egate[row];
#pragma unroll
          for (int n = 0; n < 4; ++n) {
            int col = col0 + wc * 64 + n * 16 + lr;
            atomicAdd(out + (size_t)tok * DMODEL + col, (acc[m][n][j] + bv[n]) * g);
          }
        }
      }
    }
  }
}

extern "C" void kernel_launch(void* const* d_in, const int* in_sizes, int n_in,
                              void* d_out, int out_size, void* d_ws, size_t ws_size,
                              hipStream_t stream) {
  const float* x = (const float*)d_in[0];
  const float* noise = (const float*)d_in[1];
  const float* Wr = (const float*)d_in[2];
  const float* br = (const float*)d_in[3];
  const float* Wn = (const float*)d_in[4];
  const float* bn = (const float*)d_in[5];
  const float* W1 = (const float*)d_in[6];
  const float* b1 = (const float*)d_in[7];
  const float* W2 = (const float*)d_in[8];
  const float* b2 = (const float*)d_in[9];
  float* out = (float*)d_out;

  char* ws = (char*)d_ws;
  int* topi = (int*)ws;              ws += (size_t)N_TOK * 2 * 4;
  float* tgate = (float*)ws;         ws += (size_t)N_TOK * 2 * 4;
  int* tokL = (int*)ws;              ws += (size_t)NEXP * CAP * 4;
  float* gateL = (float*)ws;         ws += (size_t)NEXP * CAP * 4;
  int* counts = (int*)ws;            ws += 256;
  ushort_t* Xg = (ushort_t*)ws;      ws += (size_t)CAP * DMODEL * 2;
  ushort_t* W1t = (ushort_t*)ws;     ws += (size_t)HDIM * DMODEL * 2;   // [4096][1024]
  ushort_t* W2t = (ushort_t*)ws;     ws += (size_t)DMODEL * HDIM * 2;   // [1024][4096]
  ushort_t* H = (ushort_t*)ws;       ws += (size_t)CAP * HDIM * 2;

  hipMemsetAsync(d_out, 0, (size_t)out_size * sizeof(float), stream);

  router_kernel<<<256, 256, 0, stream>>>(x, noise, Wr, br, Wn, bn, topi, tgate);
  scan_kernel<<<1, 1024, 0, stream>>>(topi, tgate, tokL, gateL, counts);

  for (int e = 0; e < NEXP; ++e) {
    gather_kernel<<<CAP / 2, 256, 0, stream>>>(x, tokL + e * CAP, counts, e, Xg);
    transpose_cvt_kernel<<<dim3(HDIM / 32, DMODEL / 32), dim3(32, 8), 0, stream>>>(
        W1 + (size_t)e * DMODEL * HDIM, W1t, DMODEL, HDIM);
    transpose_cvt_kernel<<<dim3(DMODEL / 32, HDIM / 32), dim3(32, 8), 0, stream>>>(
        W2 + (size_t)e * HDIM * DMODEL, W2t, HDIM, DMODEL);
    moe_gemm<0><<<dim3(HDIM / 128, CAP / 128), 256, 0, stream>>>(
        Xg, W1t, DMODEL, counts, e, b1 + (size_t)e * HDIM, H, nullptr, nullptr, nullptr);
    moe_gemm<1><<<dim3(DMODEL / 128, CAP / 128), 256, 0, stream>>>(
        H, W2t, HDIM, counts, e, b2 + (size_t)e * DMODEL, nullptr,
        tokL + e * CAP, gateL + e * CAP, out);
  }
}

// Round 2
// 1255.521 us; speedup vs baseline: 1.2474x; 1.2474x over previous
//
#include <hip/hip_runtime.h>

#define N_TOK 16384
#define DMODEL 1024
#define NEXP 8
#define CAP 4096
#define HDIM 4096

typedef unsigned short ushort_t;
typedef unsigned int u32;
typedef __attribute__((ext_vector_type(8))) _Float16 half8;
typedef __attribute__((ext_vector_type(8))) ushort_t ushort8;
typedef __attribute__((ext_vector_type(4))) float f32x4;

__device__ inline ushort_t f2h_bits(float f) {
  _Float16 h = (_Float16)f;
  union { _Float16 h; ushort_t u; } cv;
  cv.h = h;
  return cv.u;
}

__device__ inline void gll16(void* lds, const void* g) {
  __builtin_amdgcn_global_load_lds((const __attribute__((address_space(1))) u32*)g,
                                   (__attribute__((address_space(3))) u32*)lds,
                                   16, 0, 0);
}

// ---------------- router v2: 4 tokens/wave, float4 LDS reads ----------------
__global__ __launch_bounds__(256) void router_kernel(
    const float* __restrict__ x, const float* __restrict__ noise,
    const float* __restrict__ Wr, const float* __restrict__ br,
    const float* __restrict__ Wn, const float* __restrict__ bn,
    int* __restrict__ topi, float* __restrict__ tgate) {
  __shared__ float wrT[NEXP][DMODEL];
  __shared__ float wnT[NEXP][DMODEL];
  int tid = threadIdx.x;
  for (int i = tid; i < NEXP * DMODEL; i += 256) {
    int d = i >> 3, e = i & 7;
    wrT[e][d] = Wr[i];
    wnT[e][d] = Wn[i];
  }
  __syncthreads();
  int wave = tid >> 6, lane = tid & 63;
  int base = (blockIdx.x * 4 + wave) * 4;
  for (int t0 = base; t0 < N_TOK; t0 += 256 * 4 * 4) {
    float aR[4][NEXP], aN[4][NEXP];
#pragma unroll
    for (int tt = 0; tt < 4; ++tt)
#pragma unroll
      for (int e = 0; e < NEXP; ++e) { aR[tt][e] = 0.f; aN[tt][e] = 0.f; }
    for (int c = 0; c < 4; ++c) {           // d-chunks of 256
      int d = c * 256 + lane * 4;
      float4 xv[4];
#pragma unroll
      for (int tt = 0; tt < 4; ++tt)
        xv[tt] = *(const float4*)&x[(size_t)(t0 + tt) * DMODEL + d];
#pragma unroll
      for (int e = 0; e < NEXP; ++e) {
        float4 wr4 = *(const float4*)&wrT[e][d];
        float4 wn4 = *(const float4*)&wnT[e][d];
#pragma unroll
        for (int tt = 0; tt < 4; ++tt) {
          aR[tt][e] = fmaf(xv[tt].x, wr4.x, aR[tt][e]);
          aR[tt][e] = fmaf(xv[tt].y, wr4.y, aR[tt][e]);
          aR[tt][e] = fmaf(xv[tt].z, wr4.z, aR[tt][e]);
          aR[tt][e] = fmaf(xv[tt].w, wr4.w, aR[tt][e]);
          aN[tt][e] = fmaf(xv[tt].x, wn4.x, aN[tt][e]);
          aN[tt][e] = fmaf(xv[tt].y, wn4.y, aN[tt][e]);
          aN[tt][e] = fmaf(xv[tt].z, wn4.z, aN[tt][e]);
          aN[tt][e] = fmaf(xv[tt].w, wn4.w, aN[tt][e]);
        }
      }
    }
#pragma unroll
    for (int tt = 0; tt < 4; ++tt)
#pragma unroll
      for (int e = 0; e < NEXP; ++e)
#pragma unroll
        for (int off = 32; off > 0; off >>= 1) {
          aR[tt][e] += __shfl_xor(aR[tt][e], off);
          aN[tt][e] += __shfl_xor(aN[tt][e], off);
        }
#pragma unroll
    for (int tt = 0; tt < 4; ++tt) {
      if (lane == tt) {
        int t = t0 + tt;
        float v0 = -1e30f, v1 = -1e30f;
        int i0 = 0, i1 = 0;
#pragma unroll
        for (int e = 0; e < NEXP; ++e) {
          float lg = aR[tt][e] + br[e];
          float nl = aN[tt][e] + bn[e];
          float sp = fmaxf(nl, 0.f) + log1pf(expf(-fabsf(nl)));
          float nz = fmaf(noise[(size_t)t * NEXP + e], sp, lg);
          if (nz > v0) { v1 = v0; i1 = i0; v0 = nz; i0 = e; }
          else if (nz > v1) { v1 = nz; i1 = e; }
        }
        float e1 = expf(v1 - v0);
        float s = 1.f + e1;
        topi[t * 2] = i0;
        topi[t * 2 + 1] = i1;
        tgate[t * 2] = 1.f / s;
        tgate[t * 2 + 1] = e1 / s;
      }
    }
  }
}

// ------------- scan: arrival-order slots per expert, capacity clamp -------------
__global__ __launch_bounds__(1024) void scan_kernel(
    const int* __restrict__ topi, const float* __restrict__ tgate,
    int* __restrict__ tokL, float* __restrict__ gateL, int* __restrict__ counts) {
  __shared__ int s[NEXP][1024];
  __shared__ int run[NEXP][1024];
  int t = threadIdx.x;
#pragma unroll
  for (int e = 0; e < NEXP; ++e) s[e][t] = 0;
#pragma unroll
  for (int i = 0; i < 16; ++i) {
    int n = t * 16 + i;
    s[topi[n * 2]][t]++;
    s[topi[n * 2 + 1]][t]++;
  }
  int myc[NEXP];
#pragma unroll
  for (int e = 0; e < NEXP; ++e) myc[e] = s[e][t];
  __syncthreads();
  for (int off = 1; off < 1024; off <<= 1) {
    int v[NEXP];
#pragma unroll
    for (int e = 0; e < NEXP; ++e) v[e] = (t >= off) ? s[e][t - off] : 0;
    __syncthreads();
#pragma unroll
    for (int e = 0; e < NEXP; ++e) s[e][t] += v[e];
    __syncthreads();
  }
#pragma unroll
  for (int e = 0; e < NEXP; ++e) run[e][t] = s[e][t] - myc[e];
  if (t == 1023) {
#pragma unroll
    for (int e = 0; e < NEXP; ++e) counts[e] = (s[e][1023] < CAP) ? s[e][1023] : CAP;
  }
#pragma unroll
  for (int i = 0; i < 16; ++i) {
    int n = t * 16 + i;
#pragma unroll
    for (int k = 0; k < 2; ++k) {
      int e = topi[n * 2 + k];
      int slot = run[e][t]++;
      if (slot < CAP) {
        tokL[e * CAP + slot] = n;
        gateL[e * CAP + slot] = tgate[n * 2 + k];
      }
    }
  }
}

// ------------- gather (z = expert) -------------
__global__ __launch_bounds__(256) void gather_kernel(
    const float* __restrict__ x, const int* __restrict__ tokL,
    const int* __restrict__ counts, int e0, ushort_t* __restrict__ Xg_base,
    size_t xg_es) {
  int e = e0 + blockIdx.z;
  const int* etok = tokL + e * CAP;
  ushort_t* Xg = Xg_base + (size_t)blockIdx.z * xg_es;
  int ne = counts[e];
  int slot = blockIdx.x * 2 + (threadIdx.x >> 7);
  if (slot >= ne) return;
  int tok = etok[slot];
  int c = (threadIdx.x & 127) * 8;
  const float4* src = (const float4*)(x + (size_t)tok * DMODEL + c);
  float4 v0 = src[0], v1 = src[1];
  ushort8 o;
  o[0] = f2h_bits(v0.x); o[1] = f2h_bits(v0.y); o[2] = f2h_bits(v0.z); o[3] = f2h_bits(v0.w);
  o[4] = f2h_bits(v1.x); o[5] = f2h_bits(v1.y); o[6] = f2h_bits(v1.z); o[7] = f2h_bits(v1.w);
  *(ushort8*)(Xg + (size_t)slot * DMODEL + c) = o;
}

// ------------- transpose fp32 [R][C] -> f16 [C][R], 64x64 tiles, z = expert -------------
__global__ __launch_bounds__(256) void transpose_cvt_kernel(
    const float* __restrict__ in_base, ushort_t* __restrict__ out_base,
    int R, int C) {
  __shared__ ushort_t ldsT[64 * 66];   // [c][r], pitch 66 (dword-stride 33: odd -> spread banks)
  const float* in = in_base + (size_t)blockIdx.z * R * C;
  ushort_t* out = out_base + (size_t)blockIdx.z * R * C;
  int t = threadIdx.x;
  int c0 = blockIdx.x * 64, r0 = blockIdx.y * 64;
  int rr = t >> 4, cc = (t & 15) * 4;
#pragma unroll
  for (int p = 0; p < 4; ++p) {
    int row = r0 + p * 16 + rr;
    float4 v = *(const float4*)&in[(size_t)row * C + c0 + cc];
    ldsT[(cc + 0) * 66 + p * 16 + rr] = f2h_bits(v.x);
    ldsT[(cc + 1) * 66 + p * 16 + rr] = f2h_bits(v.y);
    ldsT[(cc + 2) * 66 + p * 16 + rr] = f2h_bits(v.z);
    ldsT[(cc + 3) * 66 + p * 16 + rr] = f2h_bits(v.w);
  }
  __syncthreads();
  int c_o = t >> 2, r_ch = (t & 3) * 16;
  ushort8 o0, o1;
#pragma unroll
  for (int m = 0; m < 8; ++m) {
    o0[m] = ldsT[c_o * 66 + r_ch + m];
    o1[m] = ldsT[c_o * 66 + r_ch + 8 + m];
  }
  ushort_t* dst = out + (size_t)(c0 + c_o) * R + r0 + r_ch;
  *(ushort8*)dst = o0;
  *(ushort8*)(dst + 8) = o1;
}

// ------------- 128x128 f16 MFMA GEMM (m97 structure), z = expert -------------
template <int EPI>
__global__ __launch_bounds__(256) void moe_gemm(
    const ushort_t* __restrict__ A_base, size_t a_es,
    const ushort_t* __restrict__ B_base, size_t b_es, int Kdim,
    const int* __restrict__ counts, int e0,
    const float* __restrict__ bias_base, int bias_stride,
    ushort_t* __restrict__ H_base, size_t h_es,
    const int* __restrict__ tokL, const float* __restrict__ gateL,
    float* __restrict__ out) {
  int e = e0 + blockIdx.z;
  int ne = counts[e];
  int row0 = blockIdx.y * 128;
  if (row0 >= ne) return;
  const ushort_t* A = A_base + (size_t)blockIdx.z * a_es;
  const ushort_t* Bt = B_base + (size_t)blockIdx.z * b_es;
  const float* bias = bias_base + (size_t)e * bias_stride;
  int col0 = blockIdx.x * 128;
  __shared__ __align__(16) ushort_t lds_a[128 * 32];
  __shared__ __align__(16) ushort_t lds_b[128 * 32];
  int tid = threadIdx.x, wave = tid >> 6, lane = tid & 63;
  int wr = wave >> 1, wc = wave & 1;
  f32x4 acc[4][4];
#pragma unroll
  for (int m = 0; m < 4; ++m)
#pragma unroll
    for (int n = 0; n < 4; ++n) acc[m][n] = f32x4{0.f, 0.f, 0.f, 0.f};
  int srow = lane >> 2;
  int soff = (lane & 3) * 16;
  const char* Ab = (const char*)A;
  const char* Bb = (const char*)Bt;
  size_t stride = (size_t)Kdim * 2;
  int lr = lane & 15, lk = (lane >> 4) * 8;
  for (int kt = 0; kt < Kdim; kt += 32) {
#pragma unroll
    for (int i = 0; i < 2; ++i) {
      int c = wave + i * 4;
      gll16((char*)lds_a + c * 1024,
            Ab + (size_t)(row0 + c * 16 + srow) * stride + (size_t)kt * 2 + soff);
      gll16((char*)lds_b + c * 1024,
            Bb + (size_t)(col0 + c * 16 + srow) * stride + (size_t)kt * 2 + soff);
    }
    __syncthreads();
    half8 af[4], bfr[4];
#pragma unroll
    for (int m = 0; m < 4; ++m)
      af[m] = *(const half8*)&lds_a[(wr * 64 + m * 16 + lr) * 32 + lk];
#pragma unroll
    for (int n = 0; n < 4; ++n)
      bfr[n] = *(const half8*)&lds_b[(wc * 64 + n * 16 + lr) * 32 + lk];
#pragma unroll
    for (int m = 0; m < 4; ++m)
#pragma unroll
      for (int n = 0; n < 4; ++n)
        acc[m][n] = __builtin_amdgcn_mfma_f32_16x16x32_f16(af[m], bfr[n], acc[m][n], 0, 0, 0);
    __syncthreads();
  }
  int lq = (lane >> 4) * 4;
  if (EPI == 0) {
    ushort_t* H = H_base + (size_t)blockIdx.z * h_es;
#pragma unroll
    for (int n = 0; n < 4; ++n) {
      int col = col0 + wc * 64 + n * 16 + lr;
      float bv = bias[col];
#pragma unroll
      for (int m = 0; m < 4; ++m) {
#pragma unroll
        for (int j = 0; j < 4; ++j) {
          int row = row0 + wr * 64 + m * 16 + lq + j;
          float v = acc[m][n][j] + bv;
          H[(size_t)row * HDIM + col] = f2h_bits(fmaxf(v, 0.f));
        }
      }
    }
  } else {
    const int* etok = tokL + e * CAP;
    const float* egate = gateL + e * CAP;
    float bv[4];
#pragma unroll
    for (int n = 0; n < 4; ++n) bv[n] = bias[col0 + wc * 64 + n * 16 + lr];
#pragma unroll
    for (int m = 0; m < 4; ++m) {
#pragma unroll
      for (int j = 0; j < 4; ++j) {
        int row = row0 + wr * 64 + m * 16 + lq + j;
        if (row < ne) {
          int tok = etok[row];
          float g = egate[row];
#pragma unroll
          for (int n = 0; n < 4; ++n) {
            int col = col0 + wc * 64 + n * 16 + lr;
            atomicAdd(out + (size_t)tok * DMODEL + col, (acc[m][n][j] + bv[n]) * g);
          }
        }
      }
    }
  }
}

extern "C" void kernel_launch(void* const* d_in, const int* in_sizes, int n_in,
                              void* d_out, int out_size, void* d_ws, size_t ws_size,
                              hipStream_t stream) {
  const float* x = (const float*)d_in[0];
  const float* noise = (const float*)d_in[1];
  const float* Wr = (const float*)d_in[2];
  const float* br = (const float*)d_in[3];
  const float* Wn = (const float*)d_in[4];
  const float* bn = (const float*)d_in[5];
  const float* W1 = (const float*)d_in[6];
  const float* b1 = (const float*)d_in[7];
  const float* W2 = (const float*)d_in[8];
  const float* b2 = (const float*)d_in[9];
  float* out = (float*)d_out;

  char* ws = (char*)d_ws;
  int* topi = (int*)ws;              ws += (size_t)N_TOK * 2 * 4;
  float* tgate = (float*)ws;         ws += (size_t)N_TOK * 2 * 4;
  int* tokL = (int*)ws;              ws += (size_t)NEXP * CAP * 4;
  float* gateL = (float*)ws;         ws += (size_t)NEXP * CAP * 4;
  int* counts = (int*)ws;            ws += 256;

  const size_t XG_E = (size_t)CAP * DMODEL;      // f16 elems per expert
  const size_t W1_E = (size_t)HDIM * DMODEL;
  const size_t W2_E = (size_t)DMODEL * HDIM;
  const size_t H_E  = (size_t)CAP * HDIM;

  hipMemsetAsync(d_out, 0, (size_t)out_size * sizeof(float), stream);
  router_kernel<<<256, 256, 0, stream>>>(x, noise, Wr, br, Wn, bn, topi, tgate);
  scan_kernel<<<1, 1024, 0, stream>>>(topi, tgate, tokL, gateL, counts);

  size_t used = (size_t)(ws - (char*)d_ws);
  bool fast = (ws_size - used) >= ((XG_E + W1_E + W2_E + NEXP * H_E) * 2 * NEXP / NEXP + (XG_E + W1_E + W2_E) * 2 * (NEXP - 1) + 1024);
  // explicit: need (8*XG_E + 8*W1_E + 8*W2_E + 8*H_E) * 2 bytes
  fast = (ws_size - used) >= 2ull * NEXP * (XG_E + W1_E + W2_E + H_E) + 1024;

  if (fast) {
    ushort_t* Xg_all = (ushort_t*)ws;   ws += 2ull * NEXP * XG_E;
    ushort_t* W1t_all = (ushort_t*)ws;  ws += 2ull * NEXP * W1_E;
    ushort_t* W2t_all = (ushort_t*)ws;  ws += 2ull * NEXP * W2_E;
    ushort_t* H_all = (ushort_t*)ws;    ws += 2ull * NEXP * H_E;

    gather_kernel<<<dim3(CAP / 2, 1, NEXP), 256, 0, stream>>>(
        x, tokL, counts, 0, Xg_all, XG_E);
    transpose_cvt_kernel<<<dim3(HDIM / 64, DMODEL / 64, NEXP), 256, 0, stream>>>(
        W1, W1t_all, DMODEL, HDIM);
    transpose_cvt_kernel<<<dim3(DMODEL / 64, HDIM / 64, NEXP), 256, 0, stream>>>(
        W2, W2t_all, HDIM, DMODEL);
    moe_gemm<0><<<dim3(HDIM / 128, CAP / 128, NEXP), 256, 0, stream>>>(
        Xg_all, XG_E, W1t_all, W1_E, DMODEL, counts, 0, b1, HDIM,
        H_all, H_E, nullptr, nullptr, nullptr);
    moe_gemm<1><<<dim3(DMODEL / 128, CAP / 128, NEXP), 256, 0, stream>>>(
        H_all, H_E, W2t_all, W2_E, HDIM, counts, 0, b2, DMODEL,
        nullptr, 0, tokL, gateL, out);
  } else {
    ushort_t* Xg = (ushort_t*)ws;   ws += 2ull * XG_E;
    ushort_t* W1t = (ushort_t*)ws;  ws += 2ull * W1_E;
    ushort_t* W2t = (ushort_t*)ws;  ws += 2ull * W2_E;
    ushort_t* H = (ushort_t*)ws;    ws += 2ull * H_E;
    for (int e = 0; e < NEXP; ++e) {
      gather_kernel<<<dim3(CAP / 2, 1, 1), 256, 0, stream>>>(
          x, tokL, counts, e, Xg, 0);
      transpose_cvt_kernel<<<dim3(HDIM / 64, DMODEL / 64, 1), 256, 0, stream>>>(
          W1 + (size_t)e * W1_E, W1t, DMODEL, HDIM);
      transpose_cvt_kernel<<<dim3(DMODEL / 64, HDIM / 64, 1), 256, 0, stream>>>(
          W2 + (size_t)e * W2_E, W2t, HDIM, DMODEL);
      moe_gemm<0><<<dim3(HDIM / 128, CAP / 128, 1), 256, 0, stream>>>(
          Xg, 0, W1t, 0, DMODEL, counts, e, b1, HDIM,
          H, 0, nullptr, nullptr, nullptr);
      moe_gemm<1><<<dim3(DMODEL / 128, CAP / 128, 1), 256, 0, stream>>>(
          H, 0, W2t, 0, HDIM, counts, e, b2, DMODEL,
          nullptr, 0, tokL, gateL, out);
    }
  }
}